// Round 1
// baseline (54.144 us; speedup 1.0000x reference)
//
#include <hip/hip_runtime.h>

// Problem constants: inputs (B=64, N=128, N=128, L=16) f32; w (L,6,F=32); bias/diag_bias (F,)
#define BB 64
#define NN 128
#define LL 16
#define FF 32

__global__ __launch_bounds__(256) void k_rowsum(const float* __restrict__ in,
                                                float* __restrict__ rs) {
    // one wave per (b,i) row: 2048 contiguous floats = 512 float4
    const int wave = threadIdx.x >> 6;
    const int lane = threadIdx.x & 63;
    const int row  = blockIdx.x * 4 + wave;   // b*NN + i, 8192 total
    const float4* src = reinterpret_cast<const float4*>(in) + (size_t)row * 512;
    float ax = 0.f, ay = 0.f, az = 0.f, aw = 0.f;
#pragma unroll
    for (int k = 0; k < 8; ++k) {
        float4 v = src[lane + 64 * k];
        ax += v.x; ay += v.y; az += v.z; aw += v.w;
    }
    // lanes with same (lane&3) hold partials for the same l-quad; butterfly over strides 4..32
#pragma unroll
    for (int s = 4; s < 64; s <<= 1) {
        ax += __shfl_xor(ax, s);
        ay += __shfl_xor(ay, s);
        az += __shfl_xor(az, s);
        aw += __shfl_xor(aw, s);
    }
    if (lane < 4) {
        float4 o; o.x = ax; o.y = ay; o.z = az; o.w = aw;
        reinterpret_cast<float4*>(rs + (size_t)row * LL)[lane] = o;
    }
}

__global__ __launch_bounds__(256) void k_prep(const float* __restrict__ rs_raw,
                                              const float* __restrict__ w,
                                              const float* __restrict__ bias,
                                              const float* __restrict__ dbias,
                                              float* __restrict__ gA,
                                              float* __restrict__ gC,
                                              float* __restrict__ gD) {
    // grid 256: blk -> (b = blk>>2, i-quarter = blk&3)
    __shared__ __align__(16) float sRS[NN * LL];     // 2048 floats
    __shared__ __align__(16) float sW[LL * 6 * FF];  // 3072 floats
    __shared__ float sTSp[8][16];
    __shared__ float sTS[16];
    const int blk = blockIdx.x;
    const int b   = blk >> 2;
    const int iq  = blk & 3;
    const int t   = threadIdx.x;

    const float4* rsrc = reinterpret_cast<const float4*>(rs_raw + (size_t)b * (NN * LL));
    reinterpret_cast<float4*>(sRS)[t]       = rsrc[t];
    reinterpret_cast<float4*>(sRS)[t + 256] = rsrc[t + 256];
    const float4* wsrc = reinterpret_cast<const float4*>(w);
    reinterpret_cast<float4*>(sW)[t]       = wsrc[t];
    reinterpret_cast<float4*>(sW)[t + 256] = wsrc[t + 256];
    reinterpret_cast<float4*>(sW)[t + 512] = wsrc[t + 512];
    __syncthreads();

    if (t < 128) {
        const int l = t & 15, c = t >> 4;
        float s = 0.f;
        for (int ii = 0; ii < 16; ++ii) s += sRS[(c * 16 + ii) * LL + l];
        sTSp[c][l] = s;
    }
    __syncthreads();
    if (t < 16) {
        float s = 0.f;
#pragma unroll
        for (int c = 0; c < 8; ++c) s += sTSp[c][t];
        sTS[t] = s;  // totsum_raw[b][l]
    }
    __syncthreads();

    const float invN  = 1.f / 50.f;
    const float invN2 = 1.f / 2500.f;
    // tasks: 32 i x 32 f = 1024, 4 per thread
    for (int task = t; task < 1024; task += 256) {
        const int il = task >> 5, f = task & 31;
        const int i  = iq * 32 + il;
        float dA = 0.f, dC = 0.f, dD = 0.f, tA = 0.f, tD = 0.f;
#pragma unroll
        for (int l = 0; l < LL; ++l) {
            const float r  = sRS[i * LL + l];
            const float ts = sTS[l];
            dA += r  * sW[l * 192 + 2 * 32 + f];
            dC += r  * sW[l * 192 + 3 * 32 + f];
            dD += r  * sW[l * 192 + 4 * 32 + f];
            tA += ts * sW[l * 192 + 1 * 32 + f];
            tD += ts * sW[l * 192 + 5 * 32 + f];
        }
        const size_t o = ((size_t)b * NN + i) * FF + f;
        gA[o] = dA * invN + tA * invN2 + bias[f];
        gC[o] = dC * invN;
        gD[o] = dD * invN + tD * invN2 + dbias[f];
    }
}

__global__ __launch_bounds__(256) void k_main(const float* __restrict__ in,
                                              const float* __restrict__ w,
                                              const float* __restrict__ gA,
                                              const float* __restrict__ gC,
                                              const float* __restrict__ gD,
                                              float* __restrict__ out) {
    // one block per (b,i) row; t = p*8 + g: g = f-quad (8 quads of 4 f), p = pixel lane (32)
    __shared__ __align__(16) float sIn[NN * 20];  // pixel stride 20 floats (80 B) -> bank-conflict-free b128 reads
    const int blk = blockIdx.x;  // b*NN + i
    const int b   = blk >> 7;
    const int i   = blk & 127;
    const int t   = threadIdx.x;
    const int g   = t & 7;
    const int p   = t >> 3;

    const float* rowbase = in + (size_t)blk * (NN * LL);
    // stage 512 float4 (perfectly coalesced), into padded LDS
#pragma unroll
    for (int k = 0; k < 2; ++k) {
        const int v  = k * 256 + t;   // float4 index
        const int j  = v >> 2, lq = v & 3;
        const float4 d = reinterpret_cast<const float4*>(rowbase)[v];
        *reinterpret_cast<float4*>(&sIn[j * 20 + lq * 4]) = d;
    }

    // w0 column quad in registers: w[l][0][4g..4g+3]
    float w0r[LL][4];
#pragma unroll
    for (int l = 0; l < LL; ++l) {
        const float4 wv = *reinterpret_cast<const float4*>(w + l * 192 + g * 4);
        w0r[l][0] = wv.x; w0r[l][1] = wv.y; w0r[l][2] = wv.z; w0r[l][3] = wv.w;
    }
    const float4 A4 = reinterpret_cast<const float4*>(gA + (size_t)blk * FF)[g];
    const float4 D4 = reinterpret_cast<const float4*>(gD + (size_t)blk * FF)[g];
    __syncthreads();

#pragma unroll
    for (int it = 0; it < 4; ++it) {
        const int j = p + 32 * it;
        const float4 C4 = reinterpret_cast<const float4*>(gC + ((size_t)b * NN + j) * FF)[g];
        float in_l[LL];
#pragma unroll
        for (int lq = 0; lq < 4; ++lq) {
            const float4 d = *reinterpret_cast<const float4*>(&sIn[j * 20 + lq * 4]);
            in_l[lq * 4 + 0] = d.x; in_l[lq * 4 + 1] = d.y;
            in_l[lq * 4 + 2] = d.z; in_l[lq * 4 + 3] = d.w;
        }
        float a0 = A4.x + C4.x;
        float a1 = A4.y + C4.y;
        float a2 = A4.z + C4.z;
        float a3 = A4.w + C4.w;
        if (j == i) { a0 += D4.x; a1 += D4.y; a2 += D4.z; a3 += D4.w; }
#pragma unroll
        for (int l = 0; l < LL; ++l) {
            a0 = fmaf(in_l[l], w0r[l][0], a0);
            a1 = fmaf(in_l[l], w0r[l][1], a1);
            a2 = fmaf(in_l[l], w0r[l][2], a2);
            a3 = fmaf(in_l[l], w0r[l][3], a3);
        }
        float4 o;
        o.x = fmaxf(a0, 0.f); o.y = fmaxf(a1, 0.f);
        o.z = fmaxf(a2, 0.f); o.w = fmaxf(a3, 0.f);
        float* dst = out + (((size_t)blk * NN + j) * FF) + g * 4;
        *reinterpret_cast<float4*>(dst) = o;
    }
}

extern "C" void kernel_launch(void* const* d_in, const int* in_sizes, int n_in,
                              void* d_out, int out_size, void* d_ws, size_t ws_size,
                              hipStream_t stream) {
    const float* in    = (const float*)d_in[0];  // (64,128,128,16)
    const float* w     = (const float*)d_in[1];  // (16,6,32)
    const float* bias  = (const float*)d_in[2];  // (32,)
    const float* dbias = (const float*)d_in[3];  // (32,)
    float* out = (float*)d_out;
    float* ws  = (float*)d_ws;

    float* rs = ws;            // 8192*16      = 131072 floats
    float* gA = ws + 131072;   // 64*128*32    = 262144 floats
    float* gC = ws + 393216;   // 262144 floats
    float* gD = ws + 655360;   // 262144 floats  (total 3.5 MiB)

    hipLaunchKernelGGL(k_rowsum, dim3(2048), dim3(256), 0, stream, in, rs);
    hipLaunchKernelGGL(k_prep,   dim3(256),  dim3(256), 0, stream, rs, w, bias, dbias, gA, gC, gD);
    hipLaunchKernelGGL(k_main,   dim3(8192), dim3(256), 0, stream, in, w, gA, gC, gD, out);
}

// Round 3
// 51.624 us; speedup vs baseline: 1.0488x; 1.0488x over previous
//
#include <hip/hip_runtime.h>

// Problem constants: inputs (B=64, N=128, N=128, L=16) f32; w (L,6,F=32); bias/diag_bias (F,)
#define BB 64
#define NN 128
#define LL 16
#define FF 32

typedef float vf4 __attribute__((ext_vector_type(4)));

__global__ __launch_bounds__(256) void k_rowsum(const float* __restrict__ in,
                                                float* __restrict__ rs) {
    // one wave per (b,i) row: 2048 contiguous floats = 512 float4
    const int wave = threadIdx.x >> 6;
    const int lane = threadIdx.x & 63;
    const int row  = blockIdx.x * 4 + wave;   // b*NN + i, 8192 total
    const float4* src = reinterpret_cast<const float4*>(in) + (size_t)row * 512;
    float ax = 0.f, ay = 0.f, az = 0.f, aw = 0.f;
#pragma unroll
    for (int k = 0; k < 8; ++k) {
        float4 v = src[lane + 64 * k];
        ax += v.x; ay += v.y; az += v.z; aw += v.w;
    }
    // lanes with same (lane&3) hold partials for the same l-quad; butterfly over strides 4..32
#pragma unroll
    for (int s = 4; s < 64; s <<= 1) {
        ax += __shfl_xor(ax, s);
        ay += __shfl_xor(ay, s);
        az += __shfl_xor(az, s);
        aw += __shfl_xor(aw, s);
    }
    if (lane < 4) {
        float4 o; o.x = ax; o.y = ay; o.z = az; o.w = aw;
        reinterpret_cast<float4*>(rs + (size_t)row * LL)[lane] = o;
    }
}

__global__ __launch_bounds__(256) void k_prep(const float* __restrict__ rs_raw,
                                              const float* __restrict__ w,
                                              const float* __restrict__ bias,
                                              const float* __restrict__ dbias,
                                              float* __restrict__ gA,
                                              float* __restrict__ gC,
                                              float* __restrict__ gD) {
    // grid 256: blk -> (b = blk>>2, i-quarter = blk&3)
    __shared__ __align__(16) float sRS[NN * LL];     // 2048 floats
    __shared__ __align__(16) float sW[LL * 6 * FF];  // 3072 floats
    __shared__ float sTSp[8][16];
    __shared__ float sTS[16];
    const int blk = blockIdx.x;
    const int b   = blk >> 2;
    const int iq  = blk & 3;
    const int t   = threadIdx.x;

    const float4* rsrc = reinterpret_cast<const float4*>(rs_raw + (size_t)b * (NN * LL));
    reinterpret_cast<float4*>(sRS)[t]       = rsrc[t];
    reinterpret_cast<float4*>(sRS)[t + 256] = rsrc[t + 256];
    const float4* wsrc = reinterpret_cast<const float4*>(w);
    reinterpret_cast<float4*>(sW)[t]       = wsrc[t];
    reinterpret_cast<float4*>(sW)[t + 256] = wsrc[t + 256];
    reinterpret_cast<float4*>(sW)[t + 512] = wsrc[t + 512];
    __syncthreads();

    if (t < 128) {
        const int l = t & 15, c = t >> 4;
        float s = 0.f;
        for (int ii = 0; ii < 16; ++ii) s += sRS[(c * 16 + ii) * LL + l];
        sTSp[c][l] = s;
    }
    __syncthreads();
    if (t < 16) {
        float s = 0.f;
#pragma unroll
        for (int c = 0; c < 8; ++c) s += sTSp[c][t];
        sTS[t] = s;  // totsum_raw[b][l]
    }
    __syncthreads();

    const float invN  = 1.f / 50.f;
    const float invN2 = 1.f / 2500.f;
    // tasks: 32 i x 32 f = 1024, 4 per thread
    for (int task = t; task < 1024; task += 256) {
        const int il = task >> 5, f = task & 31;
        const int i  = iq * 32 + il;
        float dA = 0.f, dC = 0.f, dD = 0.f, tA = 0.f, tD = 0.f;
#pragma unroll
        for (int l = 0; l < LL; ++l) {
            const float r  = sRS[i * LL + l];
            const float ts = sTS[l];
            dA += r  * sW[l * 192 + 2 * 32 + f];
            dC += r  * sW[l * 192 + 3 * 32 + f];
            dD += r  * sW[l * 192 + 4 * 32 + f];
            tA += ts * sW[l * 192 + 1 * 32 + f];
            tD += ts * sW[l * 192 + 5 * 32 + f];
        }
        const size_t o = ((size_t)b * NN + i) * FF + f;
        gA[o] = dA * invN + tA * invN2 + bias[f];
        gC[o] = dC * invN;
        gD[o] = dD * invN + tD * invN2 + dbias[f];
    }
}

__global__ __launch_bounds__(256) void k_main(const float* __restrict__ in,
                                              const float* __restrict__ w,
                                              const float* __restrict__ gA,
                                              const float* __restrict__ gC,
                                              const float* __restrict__ gD,
                                              float* __restrict__ out) {
    // 2 rows per block; t = p*8 + g: g = f-quad (8 quads of 4 f), p = pixel lane (32)
    __shared__ __align__(16) float sIn[2][NN * 20];  // pixel stride 20 floats -> conflict-free b128 reads
    const int blk = blockIdx.x;        // 4096 blocks
    const int b   = blk >> 6;
    const int i0  = (blk & 63) * 2;
    const int t   = threadIdx.x;
    const int g   = t & 7;
    const int p   = t >> 3;

    const float4* rowbase =
        reinterpret_cast<const float4*>(in + ((size_t)b * NN + i0) * (NN * LL));
    // stage 2 rows = 1024 float4 (perfectly coalesced), into padded LDS
#pragma unroll
    for (int k = 0; k < 4; ++k) {
        const int v  = k * 256 + t;      // float4 index 0..1023
        const int r  = v >> 9;           // row within pair
        const int vv = v & 511;
        const int j  = vv >> 2, lq = vv & 3;
        const float4 d = rowbase[v];
        *reinterpret_cast<float4*>(&sIn[r][j * 20 + lq * 4]) = d;
    }

    // w0 column quad in registers: w[l][0][4g..4g+3]
    float w0r[LL][4];
#pragma unroll
    for (int l = 0; l < LL; ++l) {
        const float4 wv = *reinterpret_cast<const float4*>(w + l * 192 + g * 4);
        w0r[l][0] = wv.x; w0r[l][1] = wv.y; w0r[l][2] = wv.z; w0r[l][3] = wv.w;
    }
    float4 A4[2], D4[2];
#pragma unroll
    for (int r = 0; r < 2; ++r) {
        const size_t rowi = (size_t)b * NN + (i0 + r);
        A4[r] = reinterpret_cast<const float4*>(gA + rowi * FF)[g];
        D4[r] = reinterpret_cast<const float4*>(gD + rowi * FF)[g];
    }
    __syncthreads();

#pragma unroll
    for (int it = 0; it < 4; ++it) {
        const int j = p + 32 * it;
        const float4 C4 = reinterpret_cast<const float4*>(gC + ((size_t)b * NN + j) * FF)[g];
#pragma unroll
        for (int r = 0; r < 2; ++r) {
            float in_l[LL];
#pragma unroll
            for (int lq = 0; lq < 4; ++lq) {
                const float4 d = *reinterpret_cast<const float4*>(&sIn[r][j * 20 + lq * 4]);
                in_l[lq * 4 + 0] = d.x; in_l[lq * 4 + 1] = d.y;
                in_l[lq * 4 + 2] = d.z; in_l[lq * 4 + 3] = d.w;
            }
            float a0 = A4[r].x + C4.x;
            float a1 = A4[r].y + C4.y;
            float a2 = A4[r].z + C4.z;
            float a3 = A4[r].w + C4.w;
            if (j == i0 + r) { a0 += D4[r].x; a1 += D4[r].y; a2 += D4[r].z; a3 += D4[r].w; }
#pragma unroll
            for (int l = 0; l < LL; ++l) {
                a0 = fmaf(in_l[l], w0r[l][0], a0);
                a1 = fmaf(in_l[l], w0r[l][1], a1);
                a2 = fmaf(in_l[l], w0r[l][2], a2);
                a3 = fmaf(in_l[l], w0r[l][3], a3);
            }
            vf4 o;
            o.x = fmaxf(a0, 0.f); o.y = fmaxf(a1, 0.f);
            o.z = fmaxf(a2, 0.f); o.w = fmaxf(a3, 0.f);
            float* dst = out + ((((size_t)b * NN + (i0 + r)) * NN + j) * FF) + g * 4;
            __builtin_nontemporal_store(o, reinterpret_cast<vf4*>(dst));
        }
    }
}

extern "C" void kernel_launch(void* const* d_in, const int* in_sizes, int n_in,
                              void* d_out, int out_size, void* d_ws, size_t ws_size,
                              hipStream_t stream) {
    const float* in    = (const float*)d_in[0];  // (64,128,128,16)
    const float* w     = (const float*)d_in[1];  // (16,6,32)
    const float* bias  = (const float*)d_in[2];  // (32,)
    const float* dbias = (const float*)d_in[3];  // (32,)
    float* out = (float*)d_out;
    float* ws  = (float*)d_ws;

    float* rs = ws;            // 8192*16      = 131072 floats
    float* gA = ws + 131072;   // 64*128*32    = 262144 floats
    float* gC = ws + 393216;   // 262144 floats
    float* gD = ws + 655360;   // 262144 floats  (total 3.5 MiB)

    hipLaunchKernelGGL(k_rowsum, dim3(2048), dim3(256), 0, stream, in, rs);
    hipLaunchKernelGGL(k_prep,   dim3(256),  dim3(256), 0, stream, rs, w, bias, dbias, gA, gC, gD);
    hipLaunchKernelGGL(k_main,   dim3(4096), dim3(256), 0, stream, in, w, gA, gC, gD, out);
}